// Round 2
// baseline (4101.411 us; speedup 1.0000x reference)
//
#include <hip/hip_runtime.h>
#include <hip/hip_bf16.h>
#include <cstdint>

typedef __hip_bfloat16 bf16;
typedef short bf16x8 __attribute__((ext_vector_type(8)));
typedef float f32x4 __attribute__((ext_vector_type(4)));

#define L_N 4096
#define RATIO 0.0625f
#define EPS_F 0.001f

__device__ __forceinline__ void unpack8(uint4 u, float* f) {
  f[0] = __uint_as_float(u.x << 16); f[1] = __uint_as_float(u.x & 0xffff0000u);
  f[2] = __uint_as_float(u.y << 16); f[3] = __uint_as_float(u.y & 0xffff0000u);
  f[4] = __uint_as_float(u.z << 16); f[5] = __uint_as_float(u.z & 0xffff0000u);
  f[6] = __uint_as_float(u.w << 16); f[7] = __uint_as_float(u.w & 0xffff0000u);
}

__device__ __forceinline__ unsigned short f2bf(float f) {
  unsigned int u = __float_as_uint(f);
  unsigned int r = (u + 0x7fffu + ((u >> 16) & 1u)) >> 16;
  return (unsigned short)r;
}

__global__ void zero_kernel(float* __restrict__ p, int n) {
  int i = blockIdx.x * 256 + threadIdx.x;
  if (i < n) p[i] = 0.f;
}

// fp32 -> bf16 conversion, 4 elems/thread. n must be a multiple of 4.
__global__ void conv_kernel(const float* __restrict__ src,
                            unsigned short* __restrict__ dst, long n) {
  long i = ((long)blockIdx.x * 256 + threadIdx.x) * 4;
  if (i < n) {
    float4 v = *(const float4*)(src + i);
    ushort4 o;
    o.x = f2bf(v.x); o.y = f2bf(v.y); o.z = f2bf(v.z); o.w = f2bf(v.w);
    *(ushort4*)(dst + i) = o;
  }
}

// C[m][n] = sum_k A[m][k] * Bt[n][k] + bias[n]. A,Bt bf16; bias fp32;
// out bf16 or fp32 per template. M,N multiples of 128, K multiple of 32.
template <bool OUT_F32>
__global__ __launch_bounds__(256) void gemm_bt_kernel(
    const bf16* __restrict__ A, const bf16* __restrict__ Bt,
    const float* __restrict__ bias, void* __restrict__ Cout,
    int Ndim, int Kdim)
{
  const int LDA = 40;  // 128x32 tile, +8 pad: keeps 16B alignment, ~2-way banks
  __shared__ short As[128 * 40];
  __shared__ short Bs[128 * 40];
  int tid = threadIdx.x;
  int lane = tid & 63;
  int wave = tid >> 6;
  int wm = (wave >> 1) * 64;
  int wn = (wave & 1) * 64;
  long m0 = (long)blockIdx.y * 128;
  long n0 = (long)blockIdx.x * 128;

  int srow = tid >> 2;         // 0..63
  int scol = (tid & 3) * 8;    // 0,8,16,24

  f32x4 acc[4][4];
#pragma unroll
  for (int i = 0; i < 4; i++)
#pragma unroll
    for (int j = 0; j < 4; j++)
      acc[i][j] = (f32x4){0.f, 0.f, 0.f, 0.f};

  int mrow = lane & 15;
  int kq = (lane >> 4) * 8;

  for (int k0 = 0; k0 < Kdim; k0 += 32) {
    uint4 a0 = *(const uint4*)(A + (m0 + srow) * Kdim + k0 + scol);
    uint4 a1 = *(const uint4*)(A + (m0 + srow + 64) * Kdim + k0 + scol);
    uint4 b0 = *(const uint4*)(Bt + (n0 + srow) * Kdim + k0 + scol);
    uint4 b1 = *(const uint4*)(Bt + (n0 + srow + 64) * Kdim + k0 + scol);
    __syncthreads();
    *(uint4*)&As[srow * LDA + scol] = a0;
    *(uint4*)&As[(srow + 64) * LDA + scol] = a1;
    *(uint4*)&Bs[srow * LDA + scol] = b0;
    *(uint4*)&Bs[(srow + 64) * LDA + scol] = b1;
    __syncthreads();
    bf16x8 af[4], bfr[4];
#pragma unroll
    for (int mi = 0; mi < 4; mi++)
      af[mi] = *(const bf16x8*)&As[(wm + mi * 16 + mrow) * LDA + kq];
#pragma unroll
    for (int ni = 0; ni < 4; ni++)
      bfr[ni] = *(const bf16x8*)&Bs[(wn + ni * 16 + mrow) * LDA + kq];
#pragma unroll
    for (int mi = 0; mi < 4; mi++)
#pragma unroll
      for (int ni = 0; ni < 4; ni++)
        acc[mi][ni] = __builtin_amdgcn_mfma_f32_16x16x32_bf16(af[mi], bfr[ni], acc[mi][ni], 0, 0, 0);
  }

#pragma unroll
  for (int ni = 0; ni < 4; ni++) {
    long col = n0 + wn + ni * 16 + (lane & 15);
    float bv = bias[col];
#pragma unroll
    for (int mi = 0; mi < 4; mi++) {
      long row = m0 + wm + mi * 16 + (lane >> 4) * 4;
#pragma unroll
      for (int r = 0; r < 4; r++) {
        float val = acc[mi][ni][r] + bv;
        if (OUT_F32)
          ((float*)Cout)[(row + r) * Ndim + col] = val;
        else
          ((bf16*)Cout)[(row + r) * Ndim + col] = __float2bfloat16(val);
      }
    }
  }
}

// Fused k-feature + kv/ksum accumulation. One (b,h) per blockIdx.x,
// L-chunk of 512 per blockIdx.y. Thread t owns feature row m=t.
// kvbuf layout: [bh][m][65] fp32 (d=0..63 = kv, 64 = ksum), atomicAdd.
__global__ __launch_bounds__(256) void kv_kernel(
    const bf16* __restrict__ qkv, const float* __restrict__ pm,
    float* __restrict__ kvbuf)
{
  int bh = blockIdx.x;
  int b = bh / 12, h = bh % 12;
  int l0 = blockIdx.y * 512;
  int t = threadIdx.x;

  __shared__ float k_lds[32][64];
  __shared__ float v_lds[32][64];

  float pmr[64];
  {
    const float4* src = (const float4*)(pm + t * 64);
#pragma unroll
    for (int i = 0; i < 16; i++) {
      float4 v = src[i];
      pmr[i * 4 + 0] = v.x; pmr[i * 4 + 1] = v.y;
      pmr[i * 4 + 2] = v.z; pmr[i * 4 + 3] = v.w;
    }
  }
  float accv[64];
#pragma unroll
  for (int d = 0; d < 64; d++) accv[d] = 0.f;
  float accsum = 0.f;

  int srow = t >> 3;        // 0..31
  int scol = (t & 7) * 8;   // 0..56

  for (int tile = 0; tile < 16; tile++) {
    long lrow = (long)(b * L_N + l0 + tile * 32 + srow) * 2304;
    uint4 kk = *(const uint4*)(qkv + lrow + 768 + h * 64 + scol);
    uint4 vv = *(const uint4*)(qkv + lrow + 1536 + h * 64 + scol);
    __syncthreads();
    unpack8(kk, &k_lds[srow][scol]);
    unpack8(vv, &v_lds[srow][scol]);
    __syncthreads();
    for (int ll = 0; ll < 32; ll++) {
      const float4* kr = (const float4*)&k_lds[ll][0];
      float s = 0.f;
#pragma unroll
      for (int j = 0; j < 16; j++) {
        float4 k4 = kr[j];
        s += k4.x * pmr[j * 4 + 0] + k4.y * pmr[j * 4 + 1]
           + k4.z * pmr[j * 4 + 2] + k4.w * pmr[j * 4 + 3];
      }
      float kp = fmaxf(s * RATIO, 0.f) + EPS_F;
      accsum += kp;
      const float4* vr = (const float4*)&v_lds[ll][0];
#pragma unroll
      for (int j = 0; j < 16; j++) {
        float4 v4 = vr[j];
        accv[j * 4 + 0] += kp * v4.x; accv[j * 4 + 1] += kp * v4.y;
        accv[j * 4 + 2] += kp * v4.z; accv[j * 4 + 3] += kp * v4.w;
      }
    }
  }
  float* dst = kvbuf + ((long)bh * 256 + t) * 65;
#pragma unroll
  for (int d = 0; d < 64; d++) atomicAdd(dst + d, accv[d]);
  atomicAdd(dst + 64, accsum);
}

// Fused q-feature + num/den + normalize. lane=d (0..63). Each wave handles
// 16 l's in groups of 4; qp broadcast through per-wave LDS; den via shfl.
__global__ __launch_bounds__(256) void attn_kernel(
    const bf16* __restrict__ qkv, const float* __restrict__ pm,
    const float* __restrict__ kvbuf, bf16* __restrict__ attn)
{
  int bh = blockIdx.x;
  int b = bh / 12, h = bh % 12;
  int l0 = blockIdx.y * 64;
  int tid = threadIdx.x;
  int lane = tid & 63;
  int wave = tid >> 6;

  __shared__ unsigned int pm_lds[256 * 33];   // bf16 pairs, stride 33 dwords
  __shared__ float qp_lds[4][256 * 4];        // per-wave qp broadcast

  {
    const float2* src = (const float2*)(pm + tid * 64);
    unsigned int* dst = &pm_lds[tid * 33];
#pragma unroll
    for (int i = 0; i < 32; i++) {
      float2 v = src[i];
      dst[i] = (unsigned int)f2bf(v.x) | ((unsigned int)f2bf(v.y) << 16);
    }
  }
  __syncthreads();

  const float* kvb = kvbuf + (long)bh * 256 * 65;
  float ksum[4];
#pragma unroll
  for (int j = 0; j < 4; j++) ksum[j] = kvb[(j * 64 + lane) * 65 + 64];

  for (int g = 0; g < 4; g++) {
    int lbase = l0 + wave * 16 + g * 4;
    float s[4][4];
#pragma unroll
    for (int li = 0; li < 4; li++)
#pragma unroll
      for (int j = 0; j < 4; j++) s[li][j] = 0.f;

#pragma unroll
    for (int k8 = 0; k8 < 8; k8++) {
      float qf[4][8];
#pragma unroll
      for (int li = 0; li < 4; li++) {
        long r = (long)(b * L_N + lbase + li);
        uint4 u = *(const uint4*)(qkv + r * 2304 + h * 64 + k8 * 8);
        unpack8(u, qf[li]);
      }
#pragma unroll
      for (int kk2 = 0; kk2 < 4; kk2++) {
#pragma unroll
        for (int j = 0; j < 4; j++) {
          unsigned int w = pm_lds[(j * 64 + lane) * 33 + k8 * 4 + kk2];
          float p0 = __uint_as_float(w << 16);
          float p1 = __uint_as_float(w & 0xffff0000u);
#pragma unroll
          for (int li = 0; li < 4; li++)
            s[li][j] += qf[li][kk2 * 2] * p0 + qf[li][kk2 * 2 + 1] * p1;
        }
      }
    }

    float qp[4][4];
#pragma unroll
    for (int li = 0; li < 4; li++)
#pragma unroll
      for (int j = 0; j < 4; j++)
        qp[li][j] = fmaxf(s[li][j] * RATIO, 0.f) + EPS_F;

    float den[4];
#pragma unroll
    for (int li = 0; li < 4; li++) {
      float dp = 0.f;
#pragma unroll
      for (int j = 0; j < 4; j++) dp += qp[li][j] * ksum[j];
      dp += __shfl_xor(dp, 32);
      dp += __shfl_xor(dp, 16);
      dp += __shfl_xor(dp, 8);
      dp += __shfl_xor(dp, 4);
      dp += __shfl_xor(dp, 2);
      dp += __shfl_xor(dp, 1);
      den[li] = dp;
    }

#pragma unroll
    for (int j = 0; j < 4; j++) {
      float4 q4 = make_float4(qp[0][j], qp[1][j], qp[2][j], qp[3][j]);
      *(float4*)&qp_lds[wave][(j * 64 + lane) * 4] = q4;
    }

    float acc0 = 0.f, acc1 = 0.f, acc2 = 0.f, acc3 = 0.f;
#pragma unroll 8
    for (int m = 0; m < 256; m++) {
      float4 q4 = *(const float4*)&qp_lds[wave][m * 4];
      float kvv = kvb[m * 65 + lane];
      acc0 += q4.x * kvv; acc1 += q4.y * kvv;
      acc2 += q4.z * kvv; acc3 += q4.w * kvv;
    }
    float accs[4] = {acc0, acc1, acc2, acc3};
#pragma unroll
    for (int li = 0; li < 4; li++) {
      long r = (long)(b * L_N + lbase + li);
      attn[r * 768 + h * 64 + lane] = __float2bfloat16(accs[li] / den[li]);
    }
  }
}

extern "C" void kernel_launch(void* const* d_in, const int* in_sizes, int n_in,
                              void* d_out, int out_size, void* d_ws, size_t ws_size,
                              hipStream_t stream)
{
  const float* x      = (const float*)d_in[0];
  const float* qkv_w  = (const float*)d_in[1];
  const float* qkv_b  = (const float*)d_in[2];
  const float* proj_w = (const float*)d_in[3];
  const float* proj_b = (const float*)d_in[4];
  const float* pmat   = (const float*)d_in[5];
  float* out = (float*)d_out;

  // ws layout (total ~212.4 MB):
  //   qkv   bf16  [0, 150994944)
  //   xbuf  bf16  [150994944, 201326592)  -- aliased: attn reuses this region
  //   kvbuf fp32  [201326592, 207716352)
  //   wqkv  bf16  [207716352, 211255296)
  //   wproj bf16  [211255296, 212434944)
  char* ws = (char*)d_ws;
  bf16*  qkv   = (bf16*)ws;
  bf16*  xbuf  = (bf16*)(ws + 150994944);
  bf16*  attn  = xbuf;  // disjoint lifetime: xbuf dead after gemm1
  float* kvbuf = (float*)(ws + 201326592);
  bf16*  wqkv  = (bf16*)(ws + 207716352);
  bf16*  wproj = (bf16*)(ws + 211255296);

  int nz = 96 * 256 * 65;
  zero_kernel<<<dim3((nz + 255) / 256), 256, 0, stream>>>(kvbuf, nz);

  conv_kernel<<<dim3(25165824 / 4 / 256), 256, 0, stream>>>(x, (unsigned short*)xbuf, 25165824L);
  conv_kernel<<<dim3(1769472 / 4 / 256), 256, 0, stream>>>(qkv_w, (unsigned short*)wqkv, 1769472L);
  conv_kernel<<<dim3(589824 / 4 / 256), 256, 0, stream>>>(proj_w, (unsigned short*)wproj, 589824L);

  // QKV projection: (32768 x 768) @ (2304 x 768)^T -> bf16 qkv
  gemm_bt_kernel<false><<<dim3(2304 / 128, 32768 / 128), 256, 0, stream>>>(
      xbuf, wqkv, qkv_b, qkv, 2304, 768);
  // kv + ksum
  kv_kernel<<<dim3(96, 8), 256, 0, stream>>>(qkv, pmat, kvbuf);
  // q features + num/den + normalize -> bf16 attn
  attn_kernel<<<dim3(96, 64), 256, 0, stream>>>(qkv, pmat, kvbuf, attn);
  // output projection: (32768 x 768) @ (768 x 768)^T -> fp32 out
  gemm_bt_kernel<true><<<dim3(768 / 128, 32768 / 128), 256, 0, stream>>>(
      attn, wproj, proj_b, out, 768, 768);
}

// Round 3
// 628.261 us; speedup vs baseline: 6.5282x; 6.5282x over previous
//
#include <hip/hip_runtime.h>
#include <hip/hip_bf16.h>
#include <cstdint>

typedef __hip_bfloat16 bf16;
typedef short bf16x8 __attribute__((ext_vector_type(8)));
typedef float f32x4 __attribute__((ext_vector_type(4)));

#define RATIO 0.0625f
#define EPS_F 0.001f

__device__ __forceinline__ void unpack8(uint4 u, float* f) {
  f[0] = __uint_as_float(u.x << 16); f[1] = __uint_as_float(u.x & 0xffff0000u);
  f[2] = __uint_as_float(u.y << 16); f[3] = __uint_as_float(u.y & 0xffff0000u);
  f[4] = __uint_as_float(u.z << 16); f[5] = __uint_as_float(u.z & 0xffff0000u);
  f[6] = __uint_as_float(u.w << 16); f[7] = __uint_as_float(u.w & 0xffff0000u);
}

__device__ __forceinline__ unsigned short f2bf(float f) {
  unsigned int u = __float_as_uint(f);
  unsigned int r = (u + 0x7fffu + ((u >> 16) & 1u)) >> 16;
  return (unsigned short)r;
}

__global__ void zero_kernel(float* __restrict__ p, int n) {
  int i = blockIdx.x * 256 + threadIdx.x;
  if (i < n) p[i] = 0.f;
}

// fp32 -> bf16 conversion, 4 elems/thread. n must be a multiple of 4.
__global__ void conv_kernel(const float* __restrict__ src,
                            unsigned short* __restrict__ dst, long n) {
  long i = ((long)blockIdx.x * 256 + threadIdx.x) * 4;
  if (i < n) {
    float4 v = *(const float4*)(src + i);
    ushort4 o;
    o.x = f2bf(v.x); o.y = f2bf(v.y); o.z = f2bf(v.z); o.w = f2bf(v.w);
    *(ushort4*)(dst + i) = o;
  }
}

// C[m][n] = sum_k A[m][k] * Bt[n][k] + bias[n]. A,Bt bf16; bias fp32;
// out bf16 or fp32 per template. M,N multiples of 128, K multiple of 32.
template <bool OUT_F32>
__global__ __launch_bounds__(256) void gemm_bt_kernel(
    const bf16* __restrict__ A, const bf16* __restrict__ Bt,
    const float* __restrict__ bias, void* __restrict__ Cout,
    int Ndim, int Kdim)
{
  const int LDA = 40;
  __shared__ short As[128 * 40];
  __shared__ short Bs[128 * 40];
  int tid = threadIdx.x;
  int lane = tid & 63;
  int wave = tid >> 6;
  int wm = (wave >> 1) * 64;
  int wn = (wave & 1) * 64;
  long m0 = (long)blockIdx.y * 128;
  long n0 = (long)blockIdx.x * 128;

  int srow = tid >> 2;
  int scol = (tid & 3) * 8;

  f32x4 acc[4][4];
#pragma unroll
  for (int i = 0; i < 4; i++)
#pragma unroll
    for (int j = 0; j < 4; j++)
      acc[i][j] = (f32x4){0.f, 0.f, 0.f, 0.f};

  int mrow = lane & 15;
  int kq = (lane >> 4) * 8;

  for (int k0 = 0; k0 < Kdim; k0 += 32) {
    uint4 a0 = *(const uint4*)(A + (m0 + srow) * Kdim + k0 + scol);
    uint4 a1 = *(const uint4*)(A + (m0 + srow + 64) * Kdim + k0 + scol);
    uint4 b0 = *(const uint4*)(Bt + (n0 + srow) * Kdim + k0 + scol);
    uint4 b1 = *(const uint4*)(Bt + (n0 + srow + 64) * Kdim + k0 + scol);
    __syncthreads();
    *(uint4*)&As[srow * LDA + scol] = a0;
    *(uint4*)&As[(srow + 64) * LDA + scol] = a1;
    *(uint4*)&Bs[srow * LDA + scol] = b0;
    *(uint4*)&Bs[(srow + 64) * LDA + scol] = b1;
    __syncthreads();
    bf16x8 af[4], bfr[4];
#pragma unroll
    for (int mi = 0; mi < 4; mi++)
      af[mi] = *(const bf16x8*)&As[(wm + mi * 16 + mrow) * LDA + kq];
#pragma unroll
    for (int ni = 0; ni < 4; ni++)
      bfr[ni] = *(const bf16x8*)&Bs[(wn + ni * 16 + mrow) * LDA + kq];
#pragma unroll
    for (int mi = 0; mi < 4; mi++)
#pragma unroll
      for (int ni = 0; ni < 4; ni++)
        acc[mi][ni] = __builtin_amdgcn_mfma_f32_16x16x32_bf16(af[mi], bfr[ni], acc[mi][ni], 0, 0, 0);
  }

#pragma unroll
  for (int ni = 0; ni < 4; ni++) {
    long col = n0 + wn + ni * 16 + (lane & 15);
    float bv = bias[col];
#pragma unroll
    for (int mi = 0; mi < 4; mi++) {
      long row = m0 + wm + mi * 16 + (lane >> 4) * 4;
#pragma unroll
      for (int r = 0; r < 4; r++) {
        float val = acc[mi][ni][r] + bv;
        if (OUT_F32)
          ((float*)Cout)[(row + r) * Ndim + col] = val;
        else
          ((bf16*)Cout)[(row + r) * Ndim + col] = __float2bfloat16(val);
      }
    }
  }
}

// ---------------------------------------------------------------------------
// kv_mfma: per (b,h) x L-chunk(1024): kv^ acc via MFMA.
// MFMA1k: S[l][m] = sum_d k[l][d] pm[m][d]  (C: row=l, col=m)
// kp3[m][l] = bf16(relu(S*ratio)+eps)
// MFMA2k: kv[m][d] += sum_l kp3[m][l] * v[l][d]  (C: row=m, col=d)
// atomicAdd into kvbuf[bh][d][m] fp32; ksum[bh][m] via LDS row sums.
__global__ __launch_bounds__(256) void kv_mfma_kernel(
    const bf16* __restrict__ qkv, const bf16* __restrict__ pmb,
    float* __restrict__ kvbuf, float* __restrict__ ksumb)
{
  int bh = blockIdx.x;
  int b = bh / 12, h = bh % 12;
  int l0 = blockIdx.y * 1024;
  int tid = threadIdx.x, lane = tid & 63, w = tid >> 6;
  int quad = lane >> 4, l16 = lane & 15;

  __shared__ short k_lds[64 * 72];
  __shared__ short v_lds[64 * 72];   // stored swizzled: [l][d ^ (((l>>3)&3)<<4)]
  __shared__ short kp3[256 * 72];    // [m][l]

  f32x4 kvacc[4][4];
#pragma unroll
  for (int mt = 0; mt < 4; mt++)
#pragma unroll
    for (int dt = 0; dt < 4; dt++)
      kvacc[mt][dt] = (f32x4){0.f, 0.f, 0.f, 0.f};
  float ksum_r = 0.f;

  int srow = tid >> 2, sseg = (tid & 3) * 8;
  int swz = ((srow >> 3) & 3) << 4;

  for (int tile = 0; tile < 16; tile++) {
    long gr = ((long)(b * 4096 + l0 + tile * 64 + srow)) * 2304 + h * 64;
    uint4 kk0 = *(const uint4*)(qkv + gr + 768 + sseg);
    uint4 kk1 = *(const uint4*)(qkv + gr + 768 + sseg + 32);
    uint4 vv0 = *(const uint4*)(qkv + gr + 1536 + sseg);
    uint4 vv1 = *(const uint4*)(qkv + gr + 1536 + sseg + 32);
    __syncthreads();   // protect LDS from previous iteration readers
    *(uint4*)&k_lds[srow * 72 + sseg] = kk0;
    *(uint4*)&k_lds[srow * 72 + sseg + 32] = kk1;
    *(uint4*)&v_lds[srow * 72 + (sseg ^ swz)] = vv0;
    *(uint4*)&v_lds[srow * 72 + ((sseg + 32) ^ swz)] = vv1;
    __syncthreads();

    // MFMA1k
    bf16x8 af[4][2], bpm[4][2];
#pragma unroll
    for (int lt = 0; lt < 4; lt++)
#pragma unroll
      for (int ks = 0; ks < 2; ks++)
        af[lt][ks] = *(const bf16x8*)&k_lds[(lt * 16 + l16) * 72 + ks * 32 + quad * 8];
#pragma unroll
    for (int mt = 0; mt < 4; mt++)
#pragma unroll
      for (int ks = 0; ks < 2; ks++)
        bpm[mt][ks] = *(const bf16x8*)(pmb + (w * 64 + mt * 16 + l16) * 64 + ks * 32 + quad * 8);

#pragma unroll
    for (int lt = 0; lt < 4; lt++)
#pragma unroll
      for (int mt = 0; mt < 4; mt++) {
        f32x4 s = (f32x4){0.f, 0.f, 0.f, 0.f};
        s = __builtin_amdgcn_mfma_f32_16x16x32_bf16(af[lt][0], bpm[mt][0], s, 0, 0, 0);
        s = __builtin_amdgcn_mfma_f32_16x16x32_bf16(af[lt][1], bpm[mt][1], s, 0, 0, 0);
        ushort4 pk;
        pk.x = f2bf(fmaxf(s[0] * RATIO, 0.f) + EPS_F);
        pk.y = f2bf(fmaxf(s[1] * RATIO, 0.f) + EPS_F);
        pk.z = f2bf(fmaxf(s[2] * RATIO, 0.f) + EPS_F);
        pk.w = f2bf(fmaxf(s[3] * RATIO, 0.f) + EPS_F);
        // rows l = lt*16 + quad*4 + r, col m = w*64 + mt*16 + l16
        *(ushort4*)&kp3[(w * 64 + mt * 16 + l16) * 72 + lt * 16 + quad * 4] = pk;
      }
    __syncthreads();

    // ksum for feature row m = tid
#pragma unroll
    for (int j8 = 0; j8 < 8; j8++) {
      uint4 u = *(const uint4*)&kp3[tid * 72 + j8 * 8];
      float f[8]; unpack8(u, f);
      ksum_r += ((f[0] + f[1]) + (f[2] + f[3])) + ((f[4] + f[5]) + (f[6] + f[7]));
    }

    // MFMA2k
#pragma unroll
    for (int ls = 0; ls < 2; ls++) {
      bf16x8 a2[4];
#pragma unroll
      for (int mt = 0; mt < 4; mt++)
        a2[mt] = *(const bf16x8*)&kp3[(w * 64 + mt * 16 + l16) * 72 + ls * 32 + quad * 8];
#pragma unroll
      for (int dt = 0; dt < 4; dt++) {
        bf16x8 b2;
        int dcol = (dt * 16 + l16) ^ (quad << 4);
#pragma unroll
        for (int jj = 0; jj < 8; jj++)
          b2[jj] = v_lds[(ls * 32 + quad * 8 + jj) * 72 + dcol];
#pragma unroll
        for (int mt = 0; mt < 4; mt++)
          kvacc[mt][dt] = __builtin_amdgcn_mfma_f32_16x16x32_bf16(a2[mt], b2, kvacc[mt][dt], 0, 0, 0);
      }
    }
  }

#pragma unroll
  for (int mt = 0; mt < 4; mt++)
#pragma unroll
    for (int dt = 0; dt < 4; dt++)
#pragma unroll
      for (int r = 0; r < 4; r++)
        atomicAdd(kvbuf + ((long)bh * 64 + dt * 16 + l16) * 256 + w * 64 + mt * 16 + quad * 4 + r,
                  kvacc[mt][dt][r]);
  atomicAdd(ksumb + bh * 256 + tid, ksum_r);
}

// ---------------------------------------------------------------------------
// attn_mfma: per (b,h) x 64 L-rows.
// MFMA1: S[m][l] = sum_d pm[m][d] q[l][d]  (C: row=m, col=l)
// qp2[l][m] = bf16(relu(S*ratio)+eps)
// den[l] = sum_m qp2[l][m]*ksum[m]  (thread-parallel + LDS reduce)
// MFMA2: num[l][d] = sum_m qp2[l][m] * kvt[d][m]  (C: row=l, col=d)
__global__ __launch_bounds__(256) void attn_mfma_kernel(
    const bf16* __restrict__ qkv, const bf16* __restrict__ pmb,
    const bf16* __restrict__ kvtb, const float* __restrict__ ksumb,
    bf16* __restrict__ attn)
{
  int bh = blockIdx.x;
  int b = bh / 12, h = bh % 12;
  int l0 = blockIdx.y * 64;
  int tid = threadIdx.x, lane = tid & 63, w = tid >> 6;
  int quad = lane >> 4, l16 = lane & 15;

  __shared__ short q_lds[64 * 72];
  __shared__ short qp2[64 * 264];     // [l][m]
  __shared__ short kvt_lds[64 * 264]; // [d][m]
  __shared__ float ksum_lds[256];
  __shared__ float den_part[4][64];

  {
    int srow = tid >> 2, sseg = (tid & 3) * 8;
    long gr = ((long)(b * 4096 + l0 + srow)) * 2304 + h * 64;
    *(uint4*)&q_lds[srow * 72 + sseg]      = *(const uint4*)(qkv + gr + sseg);
    *(uint4*)&q_lds[srow * 72 + sseg + 32] = *(const uint4*)(qkv + gr + sseg + 32);
  }
  {
    int row = tid >> 2, cb = (tid & 3) * 64;
    const bf16* src = kvtb + (long)bh * 16384 + row * 256 + cb;
    short* dst = &kvt_lds[row * 264 + cb];
#pragma unroll
    for (int j = 0; j < 8; j++)
      *(uint4*)(dst + j * 8) = *(const uint4*)(src + j * 8);
  }
  ksum_lds[tid] = ksumb[bh * 256 + tid];
  __syncthreads();

  // MFMA1
  {
    bf16x8 apm[4][2], bq[4][2];
#pragma unroll
    for (int mt = 0; mt < 4; mt++)
#pragma unroll
      for (int ks = 0; ks < 2; ks++)
        apm[mt][ks] = *(const bf16x8*)(pmb + (w * 64 + mt * 16 + l16) * 64 + ks * 32 + quad * 8);
#pragma unroll
    for (int lt = 0; lt < 4; lt++)
#pragma unroll
      for (int ks = 0; ks < 2; ks++)
        bq[lt][ks] = *(const bf16x8*)&q_lds[(lt * 16 + l16) * 72 + ks * 32 + quad * 8];

#pragma unroll
    for (int mt = 0; mt < 4; mt++)
#pragma unroll
      for (int lt = 0; lt < 4; lt++) {
        f32x4 s = (f32x4){0.f, 0.f, 0.f, 0.f};
        s = __builtin_amdgcn_mfma_f32_16x16x32_bf16(apm[mt][0], bq[lt][0], s, 0, 0, 0);
        s = __builtin_amdgcn_mfma_f32_16x16x32_bf16(apm[mt][1], bq[lt][1], s, 0, 0, 0);
        ushort4 pk;
        pk.x = f2bf(fmaxf(s[0] * RATIO, 0.f) + EPS_F);
        pk.y = f2bf(fmaxf(s[1] * RATIO, 0.f) + EPS_F);
        pk.z = f2bf(fmaxf(s[2] * RATIO, 0.f) + EPS_F);
        pk.w = f2bf(fmaxf(s[3] * RATIO, 0.f) + EPS_F);
        // row l = lt*16 + l16, cols m = w*64 + mt*16 + quad*4 + r
        *(ushort4*)&qp2[(lt * 16 + l16) * 264 + w * 64 + mt * 16 + quad * 4] = pk;
      }
  }
  __syncthreads();

  // den partials
  {
    int l = tid & 63, Q = tid >> 6;
    float dp = 0.f;
#pragma unroll
    for (int j8 = 0; j8 < 8; j8++) {
      uint4 u = *(const uint4*)&qp2[l * 264 + Q * 64 + j8 * 8];
      float f[8]; unpack8(u, f);
#pragma unroll
      for (int i = 0; i < 8; i++) dp += f[i] * ksum_lds[Q * 64 + j8 * 8 + i];
    }
    den_part[Q][l] = dp;
  }

  // MFMA2: wave strip l = w*16..w*16+15
  f32x4 o[4];
#pragma unroll
  for (int dt = 0; dt < 4; dt++) o[dt] = (f32x4){0.f, 0.f, 0.f, 0.f};
#pragma unroll
  for (int ms = 0; ms < 8; ms++) {
    bf16x8 aq = *(const bf16x8*)&qp2[(w * 16 + l16) * 264 + ms * 32 + quad * 8];
#pragma unroll
    for (int dt = 0; dt < 4; dt++) {
      bf16x8 bk = *(const bf16x8*)&kvt_lds[(dt * 16 + l16) * 264 + ms * 32 + quad * 8];
      o[dt] = __builtin_amdgcn_mfma_f32_16x16x32_bf16(aq, bk, o[dt], 0, 0, 0);
    }
  }
  __syncthreads();

  float rden[4];
#pragma unroll
  for (int r = 0; r < 4; r++) {
    int l = w * 16 + quad * 4 + r;
    rden[r] = 1.f / (den_part[0][l] + den_part[1][l] + den_part[2][l] + den_part[3][l]);
  }
#pragma unroll
  for (int dt = 0; dt < 4; dt++)
#pragma unroll
    for (int r = 0; r < 4; r++) {
      int l = w * 16 + quad * 4 + r;
      attn[((long)(b * 4096 + l0 + l)) * 768 + h * 64 + dt * 16 + l16] =
          __float2bfloat16(o[dt][r] * rden[r]);
    }
}

extern "C" void kernel_launch(void* const* d_in, const int* in_sizes, int n_in,
                              void* d_out, int out_size, void* d_ws, size_t ws_size,
                              hipStream_t stream)
{
  const float* x      = (const float*)d_in[0];
  const float* qkv_w  = (const float*)d_in[1];
  const float* qkv_b  = (const float*)d_in[2];
  const float* proj_w = (const float*)d_in[3];
  const float* proj_b = (const float*)d_in[4];
  const float* pmat   = (const float*)d_in[5];
  float* out = (float*)d_out;

  // ws layout (212,434,944 B total — same footprint as round 1):
  //   qkv   bf16  [0, 150994944)
  //   xbuf  bf16  [150994944, 201326592)   (attn aliases; disjoint lifetime)
  //   kvbuf fp32  [201326592, 207618048)   96*64*256
  //   ksumb fp32  [207618048, 207716352)   96*256
  //   wqkv  bf16  [207716352, 211255296)   dead after gemm1; kvtb+pmb alias in
  //     kvtb bf16 [207716352, 210862080)   96*64*256
  //     pmb  bf16 [210862080, 210894848)   256*64
  //   wproj bf16  [211255296, 212434944)
  char* ws = (char*)d_ws;
  bf16*  qkv   = (bf16*)ws;
  bf16*  xbuf  = (bf16*)(ws + 150994944);
  bf16*  attn  = xbuf;
  float* kvbuf = (float*)(ws + 201326592);
  float* ksumb = (float*)(ws + 207618048);
  bf16*  wqkv  = (bf16*)(ws + 207716352);
  bf16*  kvtb  = (bf16*)(ws + 207716352);
  bf16*  pmb   = (bf16*)(ws + 210862080);
  bf16*  wproj = (bf16*)(ws + 211255296);

  int nz = 96 * 64 * 256 + 96 * 256;  // kvbuf + ksumb (contiguous)
  zero_kernel<<<dim3((nz + 255) / 256), 256, 0, stream>>>(kvbuf, nz);

  conv_kernel<<<dim3(25165824 / 1024), 256, 0, stream>>>(x, (unsigned short*)xbuf, 25165824L);
  conv_kernel<<<dim3(1769472 / 1024), 256, 0, stream>>>(qkv_w, (unsigned short*)wqkv, 1769472L);
  conv_kernel<<<dim3(589824 / 1024), 256, 0, stream>>>(proj_w, (unsigned short*)wproj, 589824L);

  // QKV projection: (32768 x 768) @ (2304 x 768)^T -> bf16 qkv
  gemm_bt_kernel<false><<<dim3(2304 / 128, 32768 / 128), 256, 0, stream>>>(
      xbuf, wqkv, qkv_b, qkv, 2304, 768);

  // pm -> bf16 (region overlaps wqkv tail: must be after gemm1)
  conv_kernel<<<dim3(16384 / 1024), 256, 0, stream>>>(pmat, (unsigned short*)pmb, 16384L);

  // kv + ksum (MFMA)
  kv_mfma_kernel<<<dim3(96, 4), 256, 0, stream>>>(qkv, pmb, kvbuf, ksumb);

  // kvbuf fp32 -> kvtb bf16 (overlaps wqkv front: after gemm1; after kv_mfma)
  conv_kernel<<<dim3(1572864 / 1024), 256, 0, stream>>>(kvbuf, (unsigned short*)kvtb, 1572864L);

  // q features + num/den + normalize -> bf16 attn (MFMA)
  attn_mfma_kernel<<<dim3(96, 64), 256, 0, stream>>>(qkv, pmb, kvtb, ksumb, attn);

  // output projection: (32768 x 768) @ (768 x 768)^T -> fp32 out
  gemm_bt_kernel<true><<<dim3(768 / 128, 32768 / 128), 256, 0, stream>>>(
      attn, wproj, proj_b, out, 768, 768);
}